// Round 2
// baseline (427.611 us; speedup 1.0000x reference)
//
#include <hip/hip_runtime.h>
#include <stdint.h>

#define B_   2
#define S_   2048
#define D_   2048
#define H_   16
#define HD_  128
#define SCALE_ 0.08838834764831845f

typedef short bf16x8 __attribute__((ext_vector_type(8)));
typedef float f32x4  __attribute__((ext_vector_type(4)));

#define GLOAD_LDS16(gp, lp)                                                   \
  __builtin_amdgcn_global_load_lds(                                           \
      (const __attribute__((address_space(1))) void*)(gp),                    \
      (__attribute__((address_space(3))) void*)(lp), 16, 0, 0)

__device__ __forceinline__ ushort f2bf(float f) {
  union { float f; uint32_t u; } v; v.f = f;
  uint32_t u = v.u;
  uint32_t r = (u + 0x7FFFu + ((u >> 16) & 1u)) >> 16;
  return (ushort)r;
}

// ---------------- cast fp32 -> bf16 (straight) ----------------
__global__ __launch_bounds__(256) void cast_bf16_kernel(
    const float* __restrict__ in, ushort* __restrict__ out, int n4) {
  int i = blockIdx.x * blockDim.x + threadIdx.x;
  int stride = gridDim.x * blockDim.x;
  for (; i < n4; i += stride) {
    float4 f = ((const float4*)in)[i];
    ushort4 o;
    o.x = f2bf(f.x); o.y = f2bf(f.y); o.z = f2bf(f.z); o.w = f2bf(f.w);
    ((ushort4*)out)[i] = o;
  }
}

// ---------------- cast + transpose: in [K][N] fp32 -> out [N][K] bf16 ------
__global__ __launch_bounds__(256) void transpose_cast_kernel(
    const float* __restrict__ in, ushort* __restrict__ out, int K, int N) {
  __shared__ float tile[32][33];
  int n0 = blockIdx.x * 32, k0 = blockIdx.y * 32;
  int tx = threadIdx.x, ty = threadIdx.y;  // (32,8)
#pragma unroll
  for (int j = 0; j < 4; ++j)
    tile[ty + 8 * j][tx] = in[(size_t)(k0 + ty + 8 * j) * N + n0 + tx];
  __syncthreads();
#pragma unroll
  for (int j = 0; j < 4; ++j)
    out[(size_t)(n0 + ty + 8 * j) * K + k0 + tx] = f2bf(tile[tx][ty + 8 * j]);
}

// ---------------- GEMM: C[M,N] = A[M,K] @ Bt[N,K]^T (bf16 in, f32 acc) -----
// m97 structure: 128x128 tile, BK=64, 4 waves, global_load_lds w16,
// XOR-swizzled LDS via pre-swizzled global source (rule 21).
// MODE 0: write bf16 C, scaled.  MODE 1: KV split epilogue.  MODE 2: fp32 C.
template <int MODE>
__global__ __launch_bounds__(256) void gemm_bt(
    const ushort* __restrict__ A, const ushort* __restrict__ Bt,
    void* __restrict__ Cv, int M, int N, int K, float scale,
    ushort* __restrict__ Kout, ushort* __restrict__ Vtout) {
  __shared__ ushort As[128 * 64];
  __shared__ ushort Bs[128 * 64];
  const int tid = threadIdx.x;
  const int lane = tid & 63;
  const int wave = tid >> 6;
  const int wm = wave >> 1, wn = wave & 1;
  const int m0 = blockIdx.y * 128, n0 = blockIdx.x * 128;

  const f32x4 fzero = {0.f, 0.f, 0.f, 0.f};
  f32x4 acc[4][4];
#pragma unroll
  for (int i = 0; i < 4; ++i)
#pragma unroll
    for (int j = 0; j < 4; ++j) acc[i][j] = fzero;

  const int KT = K >> 6;

  auto stage = [&](int kt) {
    const int kbase = kt * 64;
#pragma unroll
    for (int i = 0; i < 4; ++i) {
      int s = i * 256 + tid;
      int row = s >> 3;             // 8 chunks of 8 ushorts per 64-elem row
      int gs = (s & 7) ^ (row & 7); // pre-swizzled global source (rule 21)
      GLOAD_LDS16(A + (size_t)(m0 + row) * K + kbase + gs * 8,
                  &As[(i * 256 + (tid & ~63)) * 8]);
    }
#pragma unroll
    for (int i = 0; i < 4; ++i) {
      int s = i * 256 + tid;
      int row = s >> 3;
      int gs = (s & 7) ^ (row & 7);
      GLOAD_LDS16(Bt + (size_t)(n0 + row) * K + kbase + gs * 8,
                  &Bs[(i * 256 + (tid & ~63)) * 8]);
    }
  };

  stage(0);
  for (int kt = 0; kt < KT; ++kt) {
    __syncthreads();
#pragma unroll
    for (int ks = 0; ks < 2; ++ks) {
      bf16x8 av[4], bv[4];
#pragma unroll
      for (int mf = 0; mf < 4; ++mf) {
        int row = wm * 64 + mf * 16 + (lane & 15);
        int gsw = (ks * 4 + (lane >> 4)) ^ (row & 7);
        av[mf] = *(const bf16x8*)&As[row * 64 + gsw * 8];
      }
#pragma unroll
      for (int nf = 0; nf < 4; ++nf) {
        int row = wn * 64 + nf * 16 + (lane & 15);
        int gsw = (ks * 4 + (lane >> 4)) ^ (row & 7);
        bv[nf] = *(const bf16x8*)&Bs[row * 64 + gsw * 8];
      }
#pragma unroll
      for (int mf = 0; mf < 4; ++mf)
#pragma unroll
        for (int nf = 0; nf < 4; ++nf)
          acc[mf][nf] = __builtin_amdgcn_mfma_f32_16x16x32_bf16(
              av[mf], bv[nf], acc[mf][nf], 0, 0, 0);
    }
    if (kt + 1 < KT) {
      __syncthreads();
      stage(kt + 1);
    }
  }

#pragma unroll
  for (int mf = 0; mf < 4; ++mf)
#pragma unroll
    for (int nf = 0; nf < 4; ++nf)
#pragma unroll
      for (int r = 0; r < 4; ++r) {
        int m = m0 + wm * 64 + mf * 16 + (lane >> 4) * 4 + r;
        int n = n0 + wn * 64 + nf * 16 + (lane & 15);
        float v = acc[mf][nf][r];
        if (MODE == 0) {
          ((ushort*)Cv)[(size_t)m * N + n] = f2bf(v * scale);
        } else if (MODE == 2) {
          ((float*)Cv)[(size_t)m * N + n] = v;
        } else {
          int b = m >> 11, t = m & 2047;
          if (n < 128)
            Kout[(size_t)m * 128 + n] = f2bf(v);       // K  [b*S+t][128]
          else
            Vtout[(size_t)(b * 128 + (n - 128)) * 2048 + t] = f2bf(v);  // Vt [b][128][S]
        }
      }
}

// ---------------- flash attention (MQA): per block = one (b,h), 64 q-rows --
__global__ __launch_bounds__(256) void attn_kernel(
    const ushort* __restrict__ Qbf, const ushort* __restrict__ Kbf,
    const ushort* __restrict__ Vt, ushort* __restrict__ Obf) {
  __shared__ ushort Ks[64 * 128];
  __shared__ ushort Vs[128 * 64];
  __shared__ ushort Ps[4][16 * 72];  // per-wave P tile, padded (+8 bf16)

  const int tid = threadIdx.x, lane = tid & 63, wave = tid >> 6;
  const int bh = blockIdx.y;
  const int b = bh >> 4, h = bh & 15;
  const int q0 = blockIdx.x * 64 + wave * 16;

  // Q fragments (already pre-scaled by SCALE in the Q-proj epilogue)
  bf16x8 qf[4];
  {
    const ushort* qp = Qbf + (size_t)(b * S_ + q0 + (lane & 15)) * D_ + h * HD_;
#pragma unroll
    for (int ks = 0; ks < 4; ++ks)
      qf[ks] = *(const bf16x8*)(qp + ks * 32 + (lane >> 4) * 8);
  }

  const f32x4 fzero = {0.f, 0.f, 0.f, 0.f};
  f32x4 oacc[8];
#pragma unroll
  for (int i = 0; i < 8; ++i) oacc[i] = fzero;
  float mrow[4] = {-1e30f, -1e30f, -1e30f, -1e30f};
  float lrow[4] = {0.f, 0.f, 0.f, 0.f};

  for (int t0 = 0; t0 < S_; t0 += 64) {
    // stage K tile [64][128] (swizzled source) and V tile [128][64]
#pragma unroll
    for (int i = 0; i < 4; ++i) {
      int s = i * 256 + tid;
      int tr = s >> 4;               // 16 chunks per 128-elem row
      int gs = (s & 15) ^ (tr & 7);
      GLOAD_LDS16(Kbf + (size_t)(b * S_ + t0 + tr) * HD_ + gs * 8,
                  &Ks[(i * 256 + (tid & ~63)) * 8]);
    }
#pragma unroll
    for (int i = 0; i < 4; ++i) {
      int s = i * 256 + tid;
      int d = s >> 3;                // 8 chunks per 64-elem row
      int gs = (s & 7) ^ (d & 7);
      GLOAD_LDS16(Vt + (size_t)(b * HD_ + d) * S_ + t0 + gs * 8,
                  &Vs[(i * 256 + (tid & ~63)) * 8]);
    }
    __syncthreads();

    // QK^T -> sc[4] (16 q x 64 t)
    f32x4 sc[4];
#pragma unroll
    for (int tb = 0; tb < 4; ++tb) {
      sc[tb] = fzero;
#pragma unroll
      for (int ks = 0; ks < 4; ++ks) {
        int tr = tb * 16 + (lane & 15);
        int gsw = (ks * 4 + (lane >> 4)) ^ (tr & 7);
        bf16x8 kf = *(const bf16x8*)&Ks[tr * 128 + gsw * 8];
        sc[tb] = __builtin_amdgcn_mfma_f32_16x16x32_bf16(qf[ks], kf, sc[tb], 0, 0, 0);
      }
    }

    // online softmax (wave-parallel over the 16-lane col groups)
    float mt[4];
#pragma unroll
    for (int r = 0; r < 4; ++r)
      mt[r] = fmaxf(fmaxf(sc[0][r], sc[1][r]), fmaxf(sc[2][r], sc[3][r]));
#pragma unroll
    for (int msk = 1; msk < 16; msk <<= 1)
#pragma unroll
      for (int r = 0; r < 4; ++r) mt[r] = fmaxf(mt[r], __shfl_xor(mt[r], msk));

    float alpha[4], rs[4];
#pragma unroll
    for (int r = 0; r < 4; ++r) {
      float mn = fmaxf(mrow[r], mt[r]);
      alpha[r] = __expf(mrow[r] - mn);
      mrow[r] = mn;
      rs[r] = 0.f;
    }
#pragma unroll
    for (int tb = 0; tb < 4; ++tb)
#pragma unroll
      for (int r = 0; r < 4; ++r) {
        float p = __expf(sc[tb][r] - mrow[r]);
        rs[r] += p;
        Ps[wave][((lane >> 4) * 4 + r) * 72 + tb * 16 + (lane & 15)] = f2bf(p);
      }
#pragma unroll
    for (int msk = 1; msk < 16; msk <<= 1)
#pragma unroll
      for (int r = 0; r < 4; ++r) rs[r] += __shfl_xor(rs[r], msk);
#pragma unroll
    for (int r = 0; r < 4; ++r) lrow[r] = lrow[r] * alpha[r] + rs[r];
#pragma unroll
    for (int db = 0; db < 8; ++db)
#pragma unroll
      for (int r = 0; r < 4; ++r) oacc[db][r] *= alpha[r];

    // PV: oacc[db] += P @ V   (P from per-wave LDS bounce, V from Vs)
#pragma unroll
    for (int ts = 0; ts < 2; ++ts) {
      bf16x8 pa = *(const bf16x8*)&Ps[wave][(lane & 15) * 72 + ts * 32 + (lane >> 4) * 8];
#pragma unroll
      for (int db = 0; db < 8; ++db) {
        int d = db * 16 + (lane & 15);
        int gsw = (ts * 4 + (lane >> 4)) ^ (d & 7);
        bf16x8 vf = *(const bf16x8*)&Vs[d * 64 + gsw * 8];
        oacc[db] = __builtin_amdgcn_mfma_f32_16x16x32_bf16(pa, vf, oacc[db], 0, 0, 0);
      }
    }
    __syncthreads();
  }

#pragma unroll
  for (int db = 0; db < 8; ++db)
#pragma unroll
    for (int r = 0; r < 4; ++r) {
      int q = q0 + (lane >> 4) * 4 + r;
      int d = h * HD_ + db * 16 + (lane & 15);
      Obf[(size_t)(b * S_ + q) * D_ + d] = f2bf(oacc[db][r] / lrow[r]);
    }
}

// ---------------------------------------------------------------------------
extern "C" void kernel_launch(void* const* d_in, const int* in_sizes, int n_in,
                              void* d_out, int out_size, void* d_ws, size_t ws_size,
                              hipStream_t stream) {
  const float* Qin = (const float*)d_in[0];
  const float* Wq  = (const float*)d_in[1];
  const float* Wk  = (const float*)d_in[2];
  const float* Wv  = (const float*)d_in[3];
  const float* Wo  = (const float*)d_in[4];
  float* out = (float*)d_out;

  const size_t MS = (size_t)B_ * S_;  // 4096
  char* ws = (char*)d_ws;
  ushort* Xbf  = (ushort*)ws;                 ws += MS * D_ * 2;         // 16.8 MB
  ushort* Wqt  = (ushort*)ws;                 ws += (size_t)D_ * D_ * 2; //  8.4 MB
  ushort* Wkvt = (ushort*)ws;                 ws += (size_t)256 * D_ * 2;//  1.0 MB
  ushort* Wot  = (ushort*)ws;                 ws += (size_t)D_ * D_ * 2; //  8.4 MB
  ushort* Qbf  = (ushort*)ws;                 ws += MS * D_ * 2;         // 16.8 MB
  ushort* Kbf  = (ushort*)ws;                 ws += MS * HD_ * 2;        //  1.0 MB
  ushort* Vtb  = (ushort*)ws;                 ws += MS * HD_ * 2;        //  1.0 MB
  // Obf aliases Xbf: Xbf's last reader (KV GEMM) precedes attn on the stream.
  ushort* Obf  = Xbf;                         // total ws ~53.4 MB

  // casts / transposes
  cast_bf16_kernel<<<2048, 256, 0, stream>>>(Qin, Xbf, (int)(MS * D_ / 4));
  transpose_cast_kernel<<<dim3(64, 64), dim3(32, 8), 0, stream>>>(Wq, Wqt, D_, D_);
  transpose_cast_kernel<<<dim3(4, 64),  dim3(32, 8), 0, stream>>>(Wk, Wkvt, D_, HD_);
  transpose_cast_kernel<<<dim3(4, 64),  dim3(32, 8), 0, stream>>>(Wv, Wkvt + (size_t)HD_ * D_, D_, HD_);
  transpose_cast_kernel<<<dim3(64, 64), dim3(32, 8), 0, stream>>>(Wo, Wot, D_, D_);

  // Q projection (scale folded in), KV projection (K natural, V transposed)
  gemm_bt<0><<<dim3(16, 32), 256, 0, stream>>>(Xbf, Wqt, Qbf, 4096, 2048, 2048,
                                               SCALE_, nullptr, nullptr);
  gemm_bt<1><<<dim3(2, 32), 256, 0, stream>>>(Xbf, Wkvt, nullptr, 4096, 256, 2048,
                                              1.f, Kbf, Vtb);
  // attention
  attn_kernel<<<dim3(32, 32), 256, 0, stream>>>(Qbf, Kbf, Vtb, Obf);
  // output projection -> fp32
  gemm_bt<2><<<dim3(16, 32), 256, 0, stream>>>(Obf, Wot, out, 4096, 2048, 2048,
                                               1.f, nullptr, nullptr);
}

// Round 14
// 327.969 us; speedup vs baseline: 1.3038x; 1.3038x over previous
//
#include <hip/hip_runtime.h>
#include <stdint.h>

#define B_   2
#define S_   2048
#define D_   2048
#define H_   16
#define HD_  128
#define SCALE_ 0.08838834764831845f

typedef short bf16x8 __attribute__((ext_vector_type(8)));
typedef float f32x4  __attribute__((ext_vector_type(4)));
typedef float f32x16 __attribute__((ext_vector_type(16)));

#define GLOAD_LDS16(gp, lp)                                                   \
  __builtin_amdgcn_global_load_lds(                                           \
      (const __attribute__((address_space(1))) void*)(gp),                    \
      (__attribute__((address_space(3))) void*)(lp), 16, 0, 0)

__device__ __forceinline__ ushort f2bf(float f) {
  union { float f; uint32_t u; } v; v.f = f;
  uint32_t u = v.u;
  uint32_t r = (u + 0x7FFFu + ((u >> 16) & 1u)) >> 16;
  return (ushort)r;
}

// ---------------- cast fp32 -> bf16 (straight) ----------------
__global__ __launch_bounds__(256) void cast_bf16_kernel(
    const float* __restrict__ in, ushort* __restrict__ out, int n4) {
  int i = blockIdx.x * blockDim.x + threadIdx.x;
  int stride = gridDim.x * blockDim.x;
  for (; i < n4; i += stride) {
    float4 f = ((const float4*)in)[i];
    ushort4 o;
    o.x = f2bf(f.x); o.y = f2bf(f.y); o.z = f2bf(f.z); o.w = f2bf(f.w);
    ((ushort4*)out)[i] = o;
  }
}

// ---------------- cast + transpose: in [K][N] fp32 -> out [N][K] bf16 ------
__global__ __launch_bounds__(256) void transpose_cast_kernel(
    const float* __restrict__ in, ushort* __restrict__ out, int K, int N) {
  __shared__ float tile[32][33];
  int n0 = blockIdx.x * 32, k0 = blockIdx.y * 32;
  int tx = threadIdx.x, ty = threadIdx.y;  // (32,8)
#pragma unroll
  for (int j = 0; j < 4; ++j)
    tile[ty + 8 * j][tx] = in[(size_t)(k0 + ty + 8 * j) * N + n0 + tx];
  __syncthreads();
#pragma unroll
  for (int j = 0; j < 4; ++j)
    out[(size_t)(n0 + ty + 8 * j) * K + k0 + tx] = f2bf(tile[tx][ty + 8 * j]);
}

// ---------------- GEMM: C[M,N] = A[M,K] @ Bt[N,K]^T (bf16 in, f32 acc) -----
// MODE 0: write bf16 C, scaled.  MODE 1: KV split epilogue.  MODE 2: fp32 C.
template <int MODE>
__global__ __launch_bounds__(256) void gemm_bt(
    const ushort* __restrict__ A, const ushort* __restrict__ Bt,
    void* __restrict__ Cv, int M, int N, int K, float scale,
    ushort* __restrict__ Kout, ushort* __restrict__ Vtout) {
  __shared__ ushort As[128 * 64];
  __shared__ ushort Bs[128 * 64];
  const int tid = threadIdx.x;
  const int lane = tid & 63;
  const int wave = tid >> 6;
  const int wm = wave >> 1, wn = wave & 1;
  const int m0 = blockIdx.y * 128, n0 = blockIdx.x * 128;

  const f32x4 fzero = {0.f, 0.f, 0.f, 0.f};
  f32x4 acc[4][4];
#pragma unroll
  for (int i = 0; i < 4; ++i)
#pragma unroll
    for (int j = 0; j < 4; ++j) acc[i][j] = fzero;

  const int KT = K >> 6;

  auto stage = [&](int kt) {
    const int kbase = kt * 64;
#pragma unroll
    for (int i = 0; i < 4; ++i) {
      int s = i * 256 + tid;
      int row = s >> 3;
      int gs = (s & 7) ^ (row & 7);
      GLOAD_LDS16(A + (size_t)(m0 + row) * K + kbase + gs * 8,
                  &As[(i * 256 + (tid & ~63)) * 8]);
    }
#pragma unroll
    for (int i = 0; i < 4; ++i) {
      int s = i * 256 + tid;
      int row = s >> 3;
      int gs = (s & 7) ^ (row & 7);
      GLOAD_LDS16(Bt + (size_t)(n0 + row) * K + kbase + gs * 8,
                  &Bs[(i * 256 + (tid & ~63)) * 8]);
    }
  };

  stage(0);
  for (int kt = 0; kt < KT; ++kt) {
    __syncthreads();
#pragma unroll
    for (int ks = 0; ks < 2; ++ks) {
      bf16x8 av[4], bv[4];
#pragma unroll
      for (int mf = 0; mf < 4; ++mf) {
        int row = wm * 64 + mf * 16 + (lane & 15);
        int gsw = (ks * 4 + (lane >> 4)) ^ (row & 7);
        av[mf] = *(const bf16x8*)&As[row * 64 + gsw * 8];
      }
#pragma unroll
      for (int nf = 0; nf < 4; ++nf) {
        int row = wn * 64 + nf * 16 + (lane & 15);
        int gsw = (ks * 4 + (lane >> 4)) ^ (row & 7);
        bv[nf] = *(const bf16x8*)&Bs[row * 64 + gsw * 8];
      }
#pragma unroll
      for (int mf = 0; mf < 4; ++mf)
#pragma unroll
        for (int nf = 0; nf < 4; ++nf)
          acc[mf][nf] = __builtin_amdgcn_mfma_f32_16x16x32_bf16(
              av[mf], bv[nf], acc[mf][nf], 0, 0, 0);
    }
    if (kt + 1 < KT) {
      __syncthreads();
      stage(kt + 1);
    }
  }

#pragma unroll
  for (int mf = 0; mf < 4; ++mf)
#pragma unroll
    for (int nf = 0; nf < 4; ++nf)
#pragma unroll
      for (int r = 0; r < 4; ++r) {
        int m = m0 + wm * 64 + mf * 16 + (lane >> 4) * 4 + r;
        int n = n0 + wn * 64 + nf * 16 + (lane & 15);
        float v = acc[mf][nf][r];
        if (MODE == 0) {
          ((ushort*)Cv)[(size_t)m * N + n] = f2bf(v * scale);
        } else if (MODE == 2) {
          ((float*)Cv)[(size_t)m * N + n] = v;
        } else {
          int b = m >> 11, t = m & 2047;
          if (n < 128)
            Kout[(size_t)m * 128 + n] = f2bf(v);       // K  [b*S+t][128]
          else
            Vtout[(size_t)(b * 128 + (n - 128)) * 2048 + t] = f2bf(v);  // Vt [b][128][S]
        }
      }
}

// ---------------- flash attention (MQA), m214-style 32x32 swapped-operand --
// 4 waves x 32 q-rows/wave; KVBLK=64; double-buffered K/V; in-register
// softmax (natural-log domain, __expf -- proven in this toolchain) via
// swapped QK^T; P->A-frag via cvt_pk + shfl_xor exchange; defer-max.
__global__ __launch_bounds__(256, 2) void attn_kernel(
    const ushort* __restrict__ Qbf, const ushort* __restrict__ Kbf,
    const ushort* __restrict__ Vt, ushort* __restrict__ Obf) {
  __shared__ __align__(16) ushort Ks[2][64 * 128];   // [t][d]
  __shared__ __align__(16) ushort Vs[2][128 * 64];   // [d][t]

  const int tid = threadIdx.x, lane = tid & 63, wave = tid >> 6;
  const int hi = lane >> 5, lq = lane & 31;
  const int bh = blockIdx.y, b = bh >> 4, h = bh & 15;
  const int q0 = blockIdx.x * 128 + wave * 32;

  // hoist Q to registers: B-operand frag, col=q=lq, k=d (8 chunks of 16)
  bf16x8 qf[8];
  {
    const ushort* qp = Qbf + (size_t)(b * S_ + q0 + lq) * D_ + h * HD_ + hi * 8;
#pragma unroll
    for (int kc = 0; kc < 8; ++kc) qf[kc] = *(const bf16x8*)(qp + kc * 16);
  }

  f32x16 oacc[4];
#pragma unroll
  for (int i = 0; i < 4; ++i)
#pragma unroll
    for (int r = 0; r < 16; ++r) oacc[i][r] = 0.f;
  float mrow = -1e30f, lrow = 0.f;

  auto stage = [&](int buf, int t0) {
#pragma unroll
    for (int i = 0; i < 4; ++i) {   // K tile: 64 rows x 16 chunks
      int s = i * 256 + tid;
      int tr = s >> 4;
      int gs = (s & 15) ^ (tr & 7);
      GLOAD_LDS16(Kbf + (size_t)(b * S_ + t0 + tr) * HD_ + gs * 8,
                  &Ks[buf][(i * 256 + (tid & ~63)) * 8]);
    }
#pragma unroll
    for (int i = 0; i < 4; ++i) {   // V tile: 128 rows x 8 chunks (from Vt)
      int s = i * 256 + tid;
      int d = s >> 3;
      int gs = (s & 7) ^ (d & 7);
      GLOAD_LDS16(Vt + (size_t)(b * HD_ + d) * S_ + t0 + gs * 8,
                  &Vs[buf][(i * 256 + (tid & ~63)) * 8]);
    }
  };

  int cur = 0;
  stage(0, 0);
  for (int t = 0; t < S_ / 64; ++t) {
    __syncthreads();                       // buf[cur] ready; buf[cur^1] free
    if (t + 1 < S_ / 64) stage(cur ^ 1, (t + 1) * 64);

    // ---- QK^T swapped: p = K_tile(64t x 128d) . Q^T -> D[t'][q] ----
    f32x16 p0, p1;
#pragma unroll
    for (int r = 0; r < 16; ++r) { p0[r] = 0.f; p1[r] = 0.f; }
    __builtin_amdgcn_s_setprio(1);
#pragma unroll
    for (int kc = 0; kc < 8; ++kc) {
      int c = ((kc * 2 + hi) ^ (lq & 7)) * 8;
      bf16x8 k0 = *(const bf16x8*)&Ks[cur][lq * 128 + c];
      bf16x8 k1 = *(const bf16x8*)&Ks[cur][(32 + lq) * 128 + c];
      p0 = __builtin_amdgcn_mfma_f32_32x32x16_bf16(k0, qf[kc], p0, 0, 0, 0);
      p1 = __builtin_amdgcn_mfma_f32_32x32x16_bf16(k1, qf[kc], p1, 0, 0, 0);
    }
    __builtin_amdgcn_s_setprio(0);

    // ---- online softmax, in-register (q = lq per lane) ----
    float pmax = p0[0];
#pragma unroll
    for (int r = 1; r < 16; ++r) pmax = fmaxf(pmax, p0[r]);
#pragma unroll
    for (int r = 0; r < 16; ++r) pmax = fmaxf(pmax, p1[r]);
    pmax = fmaxf(pmax, __shfl_xor(pmax, 32));

    if (!__all(pmax - mrow <= 8.f)) {      // defer-max (T13): skip rescale
      float mn = fmaxf(mrow, pmax);        // while P bounded by e^8
      float al = __expf(mrow - mn);
      mrow = mn;
      lrow *= al;
#pragma unroll
      for (int r = 0; r < 16; ++r) {
        float ar = __shfl(al, (r & 3) + 8 * (r >> 2) + 4 * hi);
#pragma unroll
        for (int d = 0; d < 4; ++d) oacc[d][r] *= ar;
      }
    }

    float rs = 0.f;
#pragma unroll
    for (int r = 0; r < 16; ++r) { p0[r] = __expf(p0[r] - mrow); rs += p0[r]; }
#pragma unroll
    for (int r = 0; r < 16; ++r) { p1[r] = __expf(p1[r] - mrow); rs += p1[r]; }
    rs += __shfl_xor(rs, 32);
    lrow += rs;

    // ---- P -> bf16 A-frags: cvt_pk pairs + shfl_xor(32) half-exchange ----
    // cvt_pk dword i of half tb holds t-pair {crow(2i,hi), crow(2i+1,hi)},
    // crow(r,hi) = (r&3)+8*(r>>2)+4*hi (+32*tb). Per 4-dword frag group g:
    //   hi=0 needs [own g0, own g1, partner g0, partner g1]
    //   hi=1 needs [partner g2, partner g3, own g2, own g3]
    // Exchange via shfl_xor(32) (unambiguous semantics; permlane32_swap
    // direction is HW-untested -> deferred micro-opt).
    uint32_t dw[2][8];
#pragma unroll
    for (int i = 0; i < 8; ++i) {
      asm("v_cvt_pk_bf16_f32 %0, %1, %2"
          : "=v"(dw[0][i]) : "v"(p0[2 * i]), "v"(p0[2 * i + 1]));
      asm("v_cvt_pk_bf16_f32 %0, %1, %2"
          : "=v"(dw[1][i]) : "v"(p1[2 * i]), "v"(p1[2 * i + 1]));
    }
#pragma unroll
    for (int tb = 0; tb < 2; ++tb)
#pragma unroll
      for (int g = 0; g < 2; ++g) {
        uint32_t e0 = (uint32_t)__shfl_xor((int)dw[tb][g * 4 + 0], 32);
        uint32_t e1 = (uint32_t)__shfl_xor((int)dw[tb][g * 4 + 1], 32);
        uint32_t e2 = (uint32_t)__shfl_xor((int)dw[tb][g * 4 + 2], 32);
        uint32_t e3 = (uint32_t)__shfl_xor((int)dw[tb][g * 4 + 3], 32);
        dw[tb][g * 4 + 0] = hi ? e2 : dw[tb][g * 4 + 0];
        dw[tb][g * 4 + 1] = hi ? e3 : dw[tb][g * 4 + 1];
        dw[tb][g * 4 + 2] = hi ? dw[tb][g * 4 + 2] : e0;
        dw[tb][g * 4 + 3] = hi ? dw[tb][g * 4 + 3] : e1;
      }

    // ---- PV: oacc[d] += P(32q x 64t) . V(64t x 128d) ----
    __builtin_amdgcn_s_setprio(1);
#pragma unroll
    for (int tb = 0; tb < 2; ++tb)
#pragma unroll
      for (int c = 0; c < 2; ++c) {
        union { uint32_t u[4]; bf16x8 v; } fa;
#pragma unroll
        for (int w = 0; w < 4; ++w) fa.u[w] = dw[tb][c * 4 + w];
        const int ks = tb * 2 + c;
#pragma unroll
        for (int d = 0; d < 4; ++d) {
          int cc = ((ks * 2 + hi) ^ (lq & 7)) * 8;
          bf16x8 vf = *(const bf16x8*)&Vs[cur][(d * 32 + lq) * 64 + cc];
          oacc[d] = __builtin_amdgcn_mfma_f32_32x32x16_bf16(fa.v, vf, oacc[d], 0, 0, 0);
        }
      }
    __builtin_amdgcn_s_setprio(0);
    cur ^= 1;
  }

  // ---- epilogue: O[q][d] * (1/l[q]) ----
  float linv = 1.f / lrow;
#pragma unroll
  for (int r = 0; r < 16; ++r) {
    const int crow = (r & 3) + 8 * (r >> 2) + 4 * hi;
    float lr_ = __shfl(linv, crow);
    const int q = q0 + crow;
#pragma unroll
    for (int d = 0; d < 4; ++d)
      Obf[(size_t)(b * S_ + q) * D_ + h * HD_ + d * 32 + lq] =
          f2bf(oacc[d][r] * lr_);
  }
}

// ---------------------------------------------------------------------------
extern "C" void kernel_launch(void* const* d_in, const int* in_sizes, int n_in,
                              void* d_out, int out_size, void* d_ws, size_t ws_size,
                              hipStream_t stream) {
  const float* Qin = (const float*)d_in[0];
  const float* Wq  = (const float*)d_in[1];
  const float* Wk  = (const float*)d_in[2];
  const float* Wv  = (const float*)d_in[3];
  const float* Wo  = (const float*)d_in[4];
  float* out = (float*)d_out;

  const size_t MS = (size_t)B_ * S_;  // 4096
  char* ws = (char*)d_ws;
  ushort* Xbf  = (ushort*)ws;                 ws += MS * D_ * 2;         // 16.8 MB
  ushort* Wqt  = (ushort*)ws;                 ws += (size_t)D_ * D_ * 2; //  8.4 MB
  ushort* Wkvt = (ushort*)ws;                 ws += (size_t)256 * D_ * 2;//  1.0 MB
  ushort* Wot  = (ushort*)ws;                 ws += (size_t)D_ * D_ * 2; //  8.4 MB
  ushort* Qbf  = (ushort*)ws;                 ws += MS * D_ * 2;         // 16.8 MB
  ushort* Kbf  = (ushort*)ws;                 ws += MS * HD_ * 2;        //  1.0 MB
  ushort* Vtb  = (ushort*)ws;                 ws += MS * HD_ * 2;        //  1.0 MB
  // Obf aliases Xbf: Xbf's last reader (KV GEMM) precedes attn on the stream.
  ushort* Obf  = Xbf;

  // casts / transposes
  cast_bf16_kernel<<<2048, 256, 0, stream>>>(Qin, Xbf, (int)(MS * D_ / 4));
  transpose_cast_kernel<<<dim3(64, 64), dim3(32, 8), 0, stream>>>(Wq, Wqt, D_, D_);
  transpose_cast_kernel<<<dim3(4, 64),  dim3(32, 8), 0, stream>>>(Wk, Wkvt, D_, HD_);
  transpose_cast_kernel<<<dim3(4, 64),  dim3(32, 8), 0, stream>>>(Wv, Wkvt + (size_t)HD_ * D_, D_, HD_);
  transpose_cast_kernel<<<dim3(64, 64), dim3(32, 8), 0, stream>>>(Wo, Wot, D_, D_);

  // Q projection (SCALE folded in), KV projection (K natural, V transposed)
  gemm_bt<0><<<dim3(16, 32), 256, 0, stream>>>(Xbf, Wqt, Qbf, 4096, 2048, 2048,
                                               SCALE_, nullptr, nullptr);
  gemm_bt<1><<<dim3(2, 32), 256, 0, stream>>>(Xbf, Wkvt, nullptr, 4096, 256, 2048,
                                              1.f, Kbf, Vtb);
  // attention
  attn_kernel<<<dim3(16, 32), 256, 0, stream>>>(Qbf, Kbf, Vtb, Obf);
  // output projection -> fp32
  gemm_bt<2><<<dim3(16, 32), 256, 0, stream>>>(Obf, Wot, out, 4096, 2048, 2048,
                                               1.f, nullptr, nullptr);
}